// Round 1
// baseline (297.624 us; speedup 1.0000x reference)
//
#include <hip/hip_runtime.h>

typedef __bf16 bf16;
typedef __bf16 bf16x8 __attribute__((ext_vector_type(8)));
typedef __bf16 bf16x4 __attribute__((ext_vector_type(4)));
typedef float f32x4 __attribute__((ext_vector_type(4)));

static __device__ __forceinline__ bf16x8 ld8(const bf16* p) {
    return *reinterpret_cast<const bf16x8*>(p);
}
static __device__ __forceinline__ bf16x4 ld4(const bf16* p) {
    return *reinterpret_cast<const bf16x4*>(p);
}
static __device__ __forceinline__ bf16x8 zero8() {
    bf16x8 v;
#pragma unroll
    for (int i = 0; i < 8; ++i) v[i] = (bf16)0.f;
    return v;
}

#define MFMA16(a, b, c) __builtin_amdgcn_mfma_f32_16x16x32_bf16((a), (b), (c), 0, 0, 0)

// ---------------------------------------------------------------------------
// prep: weight fp32->bf16 conversion with pad/scatter, plus bias table gather.
// Layouts:
//   wkv  [384][192]  (kv_w [360][180], K tail-padded)
//   wq   [256][192]
//   wproj[256][192]  K head-padded: k = h*32+d -> src h*30+d (d<30)
//   wfc1 [768][192]
//   wfc2 [256][736]
//   biast[h][kg(36)][klo(16)][q(256)] bf16 = rpb[rpi[q][kg*16+klo]][h]
// ---------------------------------------------------------------------------
__global__ __launch_bounds__(256) void prep_kernel(
    const float* __restrict__ kv_w, const float* __restrict__ q_w,
    const float* __restrict__ proj_w, const float* __restrict__ fc1_w,
    const float* __restrict__ fc2_w, const float* __restrict__ rpb,
    const int* __restrict__ rpi,
    bf16* __restrict__ wkv, bf16* __restrict__ wq, bf16* __restrict__ wproj,
    bf16* __restrict__ wfc1, bf16* __restrict__ wfc2, bf16* __restrict__ biast)
{
    int i = blockIdx.x * 256 + threadIdx.x;
    if (i < 73728) {                       // wkv
        int n = i / 192, k = i % 192;
        float v = (n < 360 && k < 180) ? kv_w[n * 180 + k] : 0.f;
        wkv[i] = (bf16)v;
    } else if (i < 122880) {               // wq
        int j = i - 73728; int n = j / 192, k = j % 192;
        float v = (n < 180 && k < 180) ? q_w[n * 180 + k] : 0.f;
        wq[j] = (bf16)v;
    } else if (i < 172032) {               // wproj (head-padded K)
        int j = i - 122880; int n = j / 192, k = j % 192;
        int hh = k >> 5, d = k & 31;
        float v = (n < 180 && d < 30) ? proj_w[n * 180 + hh * 30 + d] : 0.f;
        wproj[j] = (bf16)v;
    } else if (i < 319488) {               // wfc1
        int j = i - 172032; int n = j / 192, k = j % 192;
        float v = (n < 720 && k < 180) ? fc1_w[n * 180 + k] : 0.f;
        wfc1[j] = (bf16)v;
    } else if (i < 507904) {               // wfc2
        int j = i - 319488; int n = j / 736, k = j % 736;
        float v = (n < 180 && k < 720) ? fc2_w[n * 720 + k] : 0.f;
        wfc2[j] = (bf16)v;
    } else if (i < 1392640) {              // bias table
        int t = i - 507904;
        int q = t & 255, klo = (t >> 8) & 15, kg = (t >> 12) % 36, h = t / 147456;
        biast[t] = (bf16)rpb[rpi[q * 576 + kg * 16 + klo] * 6 + h];
    }
}

// ---------------------------------------------------------------------------
// LayerNorm: one wave per row of 180 fp32 -> bf16 [row][192] (tail zeroed).
// Rows >= 16384 come from srcB (used to fuse LN(x) and LN(y) in one launch).
// ---------------------------------------------------------------------------
__global__ __launch_bounds__(256) void ln_kernel(
    const float* __restrict__ srcA, const float* __restrict__ srcB,
    const float* __restrict__ g, const float* __restrict__ b,
    bf16* __restrict__ dst)
{
    int wave = threadIdx.x >> 6, lane = threadIdx.x & 63;
    int row = blockIdx.x * 4 + wave;
    const float* sp = (row < 16384) ? (srcA + row * 180) : (srcB + (row - 16384) * 180);
    float v0 = sp[lane];
    float v1 = sp[lane + 64];
    float v2 = (lane < 52) ? sp[lane + 128] : 0.f;
    float s = v0 + v1 + v2;
    float sq = v0 * v0 + v1 * v1 + v2 * v2;
#pragma unroll
    for (int m = 32; m >= 1; m >>= 1) {
        s += __shfl_xor(s, m);
        sq += __shfl_xor(sq, m);
    }
    float mean = s * (1.f / 180.f);
    float var = sq * (1.f / 180.f) - mean * mean;
    float rs = rsqrtf(var + 1e-5f);
    bf16* dp = dst + (long)row * 192;
    dp[lane] = (bf16)((v0 - mean) * rs * g[lane] + b[lane]);
    dp[lane + 64] = (bf16)((v1 - mean) * rs * g[lane + 64] + b[lane + 64]);
    float o2 = (lane < 52) ? ((v2 - mean) * rs * g[lane + 128] + b[lane + 128]) : 0.f;
    dp[lane + 128] = (bf16)o2;
}

// ---------------------------------------------------------------------------
// Fused kv-proj + q-proj GEMM. Direct-global MFMA, 128x128 tile, K=192.
// blockIdx.y < 3 : C = xn @ wkv^T + kv_b  -> kvbuf [16384][384] head-padded
// blockIdx.y >= 3: C = yn @ wq^T  + q_b   -> qbuf  [16384][192] head-padded, *scale
// ---------------------------------------------------------------------------
__global__ __launch_bounds__(256) void gemm_kvq(
    const bf16* __restrict__ xn, const bf16* __restrict__ yn,
    const bf16* __restrict__ wkv, const bf16* __restrict__ wq,
    const float* __restrict__ kv_b, const float* __restrict__ q_b,
    bf16* __restrict__ kvbuf, bf16* __restrict__ qbuf)
{
    const int tid = threadIdx.x, wave = tid >> 6, lane = tid & 63;
    const int llo = lane & 15, quad = lane >> 4;
    const bool isq = blockIdx.y >= 3;
    const bf16* A = isq ? yn : xn;
    const bf16* W = isq ? wq : wkv;
    const float* bias = isq ? q_b : kv_b;
    const int tm = blockIdx.x * 128;
    const int tn = (isq ? (blockIdx.y - 3) : blockIdx.y) * 128;
    const int wm = (wave >> 1) * 64, wn = (wave & 1) * 64;

    f32x4 acc[4][4];
#pragma unroll
    for (int mt = 0; mt < 4; ++mt)
#pragma unroll
        for (int nt = 0; nt < 4; ++nt)
#pragma unroll
            for (int r = 0; r < 4; ++r) acc[mt][nt][r] = 0.f;

    for (int kt = 0; kt < 6; ++kt) {
        bf16x8 a[4], b[4];
#pragma unroll
        for (int mt = 0; mt < 4; ++mt)
            a[mt] = ld8(A + (long)(tm + wm + mt * 16 + llo) * 192 + kt * 32 + quad * 8);
#pragma unroll
        for (int nt = 0; nt < 4; ++nt)
            b[nt] = ld8(W + (long)(tn + wn + nt * 16 + llo) * 192 + kt * 32 + quad * 8);
#pragma unroll
        for (int mt = 0; mt < 4; ++mt)
#pragma unroll
            for (int nt = 0; nt < 4; ++nt)
                acc[mt][nt] = MFMA16(a[mt], b[nt], acc[mt][nt]);
    }

#pragma unroll
    for (int mt = 0; mt < 4; ++mt)
#pragma unroll
        for (int nt = 0; nt < 4; ++nt)
#pragma unroll
            for (int r = 0; r < 4; ++r) {
                int m = tm + wm + mt * 16 + quad * 4 + r;
                int n = tn + wn + nt * 16 + llo;
                if (!isq) {
                    if (n < 360) {
                        float v = acc[mt][nt][r] + bias[n];
                        int nn = n % 180;
                        int col = (n / 180) * 192 + (nn / 30) * 32 + (nn % 30);
                        kvbuf[(long)m * 384 + col] = (bf16)v;
                    }
                } else {
                    if (n < 180) {
                        float v = (acc[mt][nt][r] + bias[n]) * 0.18257418583505537f;
                        int col = (n / 30) * 32 + (n % 30);
                        qbuf[(long)m * 192 + col] = (bf16)v;
                    }
                }
            }
}

// ---------------------------------------------------------------------------
// Attention: one block per (window, head). 4 waves, 64 queries each.
// Online softmax over 9 chunks of 64 keys. Zero-padded OOB keys participate
// with score = bias (matching reference semantics).
// ---------------------------------------------------------------------------
__global__ __launch_bounds__(256) void attn_kernel(
    const bf16* __restrict__ qbuf,   // [16384][192] head-padded, pre-scaled
    const bf16* __restrict__ kvbuf,  // [16384][384] K at +0, V at +192
    const bf16* __restrict__ biast,  // [6][36][16][256]
    bf16* __restrict__ obuf)         // [16384][192] head-padded
{
    const int head = blockIdx.x % 6;
    const int win = blockIdx.x / 6;
    const int bb = win / 16, wi = (win % 16) / 4, wj = win % 4;
    const int tid = threadIdx.x;
    const int wave = tid >> 6, lane = tid & 63;
    const int llo = lane & 15, quad = lane >> 4;
    const int qbase = wave * 64;

    __shared__ bf16 Vt[32][72];       // V chunk transposed: [d][key]
    __shared__ bf16 Ps[4][64][72];    // per-wave P: [m][key]

    // Q A-fragments straight from global (16B per lane, head-padded layout)
    bf16x8 qa[4];
#pragma unroll
    for (int mt = 0; mt < 4; ++mt) {
        int qq = qbase + mt * 16 + llo;
        int gr = bb * 4096 + (wi * 16 + (qq >> 4)) * 64 + (wj * 16 + (qq & 15));
        qa[mt] = ld8(qbuf + (long)gr * 192 + head * 32 + quad * 8);
    }

    f32x4 o[4][2];
    float m_run[4][4], l_run[4][4];
#pragma unroll
    for (int mt = 0; mt < 4; ++mt) {
#pragma unroll
        for (int r = 0; r < 4; ++r) {
            o[mt][0][r] = 0.f; o[mt][1][r] = 0.f;
            m_run[mt][r] = -1e30f; l_run[mt][r] = 0.f;
        }
    }

    for (int c = 0; c < 9; ++c) {
        const int kb = c * 64;
        __syncthreads();   // prior PV reads of Vt done
        {   // stage V chunk transposed: thread -> (key, 8-d group)
            int key = kb + (tid >> 2);
            int dq = tid & 3;
            int a = key / 24, w2 = key % 24;
            int gy = wi * 16 + a - 4, gx = wj * 16 + w2 - 4;
            bf16x8 v = zero8();
            if ((unsigned)gy < 64u && (unsigned)gx < 64u) {
                int gr = bb * 4096 + gy * 64 + gx;
                v = ld8(kvbuf + (long)gr * 384 + 192 + head * 32 + dq * 8);
            }
            int kk = (tid >> 2);
#pragma unroll
            for (int j = 0; j < 8; ++j) Vt[dq * 8 + j][kk] = v[j];
        }
        __syncthreads();   // Vt ready

        // ---- QK^T for this chunk ----
        bf16x8 kf[4];
#pragma unroll
        for (int nt = 0; nt < 4; ++nt) {
            int key = kb + nt * 16 + llo;
            int a = key / 24, w2 = key % 24;
            int gy = wi * 16 + a - 4, gx = wj * 16 + w2 - 4;
            bf16x8 kv = zero8();
            if ((unsigned)gy < 64u && (unsigned)gx < 64u)
                kv = ld8(kvbuf + (long)(bb * 4096 + gy * 64 + gx) * 384 + head * 32 + quad * 8);
            kf[nt] = kv;
        }
        f32x4 s[4][4];
#pragma unroll
        for (int mt = 0; mt < 4; ++mt)
#pragma unroll
            for (int nt = 0; nt < 4; ++nt) {
                f32x4 zc;
                zc[0] = 0.f; zc[1] = 0.f; zc[2] = 0.f; zc[3] = 0.f;
                s[mt][nt] = MFMA16(qa[mt], kf[nt], zc);
            }

        // ---- + bias (one 8B load per fragment) ----
#pragma unroll
        for (int mt = 0; mt < 4; ++mt)
#pragma unroll
            for (int nt = 0; nt < 4; ++nt) {
                int kg = c * 4 + nt;
                int q0 = qbase + mt * 16 + quad * 4;
                bf16x4 bv = ld4(biast + ((long)(head * 36 + kg) * 16 + llo) * 256 + q0);
#pragma unroll
                for (int r = 0; r < 4; ++r) s[mt][nt][r] += (float)bv[r];
            }

        // ---- online softmax ----
#pragma unroll
        for (int mt = 0; mt < 4; ++mt)
#pragma unroll
            for (int r = 0; r < 4; ++r) {
                float mx = fmaxf(fmaxf(s[mt][0][r], s[mt][1][r]),
                                 fmaxf(s[mt][2][r], s[mt][3][r]));
                mx = fmaxf(mx, __shfl_xor(mx, 1));
                mx = fmaxf(mx, __shfl_xor(mx, 2));
                mx = fmaxf(mx, __shfl_xor(mx, 4));
                mx = fmaxf(mx, __shfl_xor(mx, 8));
                float m_new = fmaxf(m_run[mt][r], mx);
                float alpha = __expf(m_run[mt][r] - m_new);
                float ls = 0.f;
#pragma unroll
                for (int nt = 0; nt < 4; ++nt) {
                    float p = __expf(s[mt][nt][r] - m_new);
                    s[mt][nt][r] = p;
                    ls += p;
                }
                ls += __shfl_xor(ls, 1);
                ls += __shfl_xor(ls, 2);
                ls += __shfl_xor(ls, 4);
                ls += __shfl_xor(ls, 8);
                l_run[mt][r] = l_run[mt][r] * alpha + ls;
                m_run[mt][r] = m_new;
                o[mt][0][r] *= alpha;
                o[mt][1][r] *= alpha;
            }

        // ---- P -> LDS (C-layout scatter), then PV via A-layout reads ----
#pragma unroll
        for (int mt = 0; mt < 4; ++mt)
#pragma unroll
            for (int nt = 0; nt < 4; ++nt)
#pragma unroll
                for (int r = 0; r < 4; ++r)
                    Ps[wave][mt * 16 + quad * 4 + r][nt * 16 + llo] = (bf16)s[mt][nt][r];
        __syncthreads();

#pragma unroll
        for (int kt = 0; kt < 2; ++kt) {
            bf16x8 pa[4], vb[2];
#pragma unroll
            for (int mt = 0; mt < 4; ++mt)
                pa[mt] = ld8(&Ps[wave][mt * 16 + llo][kt * 32 + quad * 8]);
#pragma unroll
            for (int n2 = 0; n2 < 2; ++n2)
                vb[n2] = ld8(&Vt[n2 * 16 + llo][kt * 32 + quad * 8]);
#pragma unroll
            for (int mt = 0; mt < 4; ++mt)
#pragma unroll
                for (int n2 = 0; n2 < 2; ++n2)
                    o[mt][n2] = MFMA16(pa[mt], vb[n2], o[mt][n2]);
        }
    }

    // ---- normalize and write out (head-padded) ----
#pragma unroll
    for (int mt = 0; mt < 4; ++mt)
#pragma unroll
        for (int r = 0; r < 4; ++r) {
            float inv = 1.f / l_run[mt][r];
            int q = qbase + mt * 16 + quad * 4 + r;
            int gr = bb * 4096 + (wi * 16 + (q >> 4)) * 64 + (wj * 16 + (q & 15));
#pragma unroll
            for (int n2 = 0; n2 < 2; ++n2)
                obuf[(long)gr * 192 + head * 32 + n2 * 16 + llo] = (bf16)(o[mt][n2][r] * inv);
        }
}

// ---------------------------------------------------------------------------
// Generic epilogue GEMM: C = A[M][KPAD] @ W[N][KPAD]^T + bias
// MODE 2: fp32 out = v + resid   (proj+residual, fc2+residual)
// MODE 3: bf16 out = gelu(v)     (fc1)
// ---------------------------------------------------------------------------
template <int KPAD, int NREAL, int OSTRIDE, int MODE>
__global__ __launch_bounds__(256) void gemm_ep(
    const bf16* __restrict__ A, const bf16* __restrict__ W,
    const float* __restrict__ bias, const float* __restrict__ resid,
    void* __restrict__ outp)
{
    const int tid = threadIdx.x, wave = tid >> 6, lane = tid & 63;
    const int llo = lane & 15, quad = lane >> 4;
    const int tm = blockIdx.x * 128;
    const int tn = blockIdx.y * 128;
    const int wm = (wave >> 1) * 64, wn = (wave & 1) * 64;

    f32x4 acc[4][4];
#pragma unroll
    for (int mt = 0; mt < 4; ++mt)
#pragma unroll
        for (int nt = 0; nt < 4; ++nt)
#pragma unroll
            for (int r = 0; r < 4; ++r) acc[mt][nt][r] = 0.f;

    for (int kt = 0; kt < KPAD / 32; ++kt) {
        bf16x8 a[4], b[4];
#pragma unroll
        for (int mt = 0; mt < 4; ++mt)
            a[mt] = ld8(A + (long)(tm + wm + mt * 16 + llo) * KPAD + kt * 32 + quad * 8);
#pragma unroll
        for (int nt = 0; nt < 4; ++nt)
            b[nt] = ld8(W + (long)(tn + wn + nt * 16 + llo) * KPAD + kt * 32 + quad * 8);
#pragma unroll
        for (int mt = 0; mt < 4; ++mt)
#pragma unroll
            for (int nt = 0; nt < 4; ++nt)
                acc[mt][nt] = MFMA16(a[mt], b[nt], acc[mt][nt]);
    }

#pragma unroll
    for (int mt = 0; mt < 4; ++mt)
#pragma unroll
        for (int nt = 0; nt < 4; ++nt)
#pragma unroll
            for (int r = 0; r < 4; ++r) {
                int m = tm + wm + mt * 16 + quad * 4 + r;
                int n = tn + wn + nt * 16 + llo;
                if (n >= NREAL) continue;
                float v = acc[mt][nt][r] + bias[n];
                if (MODE == 2) {
                    ((float*)outp)[(long)m * OSTRIDE + n] = v + resid[(long)m * 180 + n];
                } else {
                    float gel = 0.5f * v * (1.f + erff(v * 0.7071067811865475f));
                    ((bf16*)outp)[(long)m * OSTRIDE + n] = (bf16)gel;
                }
            }
}

// ---------------------------------------------------------------------------
extern "C" void kernel_launch(void* const* d_in, const int* in_sizes, int n_in,
                              void* d_out, int out_size, void* d_ws, size_t ws_size,
                              hipStream_t stream) {
    const float* x      = (const float*)d_in[0];
    const float* y      = (const float*)d_in[1];
    const float* n1g    = (const float*)d_in[2];
    const float* n1b    = (const float*)d_in[3];
    const float* kv_w   = (const float*)d_in[4];
    const float* kv_b   = (const float*)d_in[5];
    const float* q_w    = (const float*)d_in[6];
    const float* q_b    = (const float*)d_in[7];
    const float* rpb    = (const float*)d_in[8];
    const float* proj_w = (const float*)d_in[9];
    const float* proj_b = (const float*)d_in[10];
    const float* n2g    = (const float*)d_in[11];
    const float* n2b    = (const float*)d_in[12];
    const float* fc1_w  = (const float*)d_in[13];
    const float* fc1_b  = (const float*)d_in[14];
    const float* fc2_w  = (const float*)d_in[15];
    const float* fc2_b  = (const float*)d_in[16];
    const int*   rpi    = (const int*)d_in[17];

    char* ws = (char*)d_ws;
    bf16* xn    = (bf16*)(ws + 0);          // [32768][192] = xn (16384) + yn (16384)
    bf16* yn    = (bf16*)(ws + 6291456);
    bf16* qbuf  = (bf16*)(ws + 12582912);   // [16384][192]
    bf16* kvbuf = (bf16*)(ws + 18874368);   // [16384][384]
    bf16* obuf  = (bf16*)(ws + 31457280);   // [16384][192]
    float* xo   = (float*)(ws + 37748736);  // [16384][180] fp32
    bf16* biast = (bf16*)(ws + 49545216);   // [6][36][16][256]
    bf16* wkv   = (bf16*)(ws + 51314688);
    bf16* wq    = (bf16*)(ws + 51462144);
    bf16* wproj = (bf16*)(ws + 51560448);
    bf16* wfc1  = (bf16*)(ws + 51658752);
    bf16* wfc2  = (bf16*)(ws + 51953664);
    // lifetimes: yn/qbuf/kvbuf dead after attention -> reuse for hmid [16384][736]
    bf16* hmid  = (bf16*)(ws + 6291456);
    bf16* xn2   = xn;                       // xn dead after gemm_kvq

    prep_kernel<<<5440, 256, 0, stream>>>(kv_w, q_w, proj_w, fc1_w, fc2_w, rpb, rpi,
                                          wkv, wq, wproj, wfc1, wfc2, biast);
    ln_kernel<<<8192, 256, 0, stream>>>(x, y, n1g, n1b, xn);
    gemm_kvq<<<dim3(128, 5), 256, 0, stream>>>(xn, yn, wkv, wq, kv_b, q_b, kvbuf, qbuf);
    attn_kernel<<<384, 256, 0, stream>>>(qbuf, kvbuf, biast, obuf);
    gemm_ep<192, 180, 180, 2><<<dim3(128, 2), 256, 0, stream>>>(obuf, wproj, proj_b, x, xo);
    ln_kernel<<<4096, 256, 0, stream>>>(xo, xo, n2g, n2b, xn2);
    gemm_ep<192, 720, 736, 3><<<dim3(128, 6), 256, 0, stream>>>(xn2, wfc1, fc1_b, nullptr, hmid);
    gemm_ep<736, 180, 180, 2><<<dim3(128, 2), 256, 0, stream>>>(hmid, wfc2, fc2_b, xo, (float*)d_out);
}

// Round 3
// 277.830 us; speedup vs baseline: 1.0712x; 1.0712x over previous
//
#include <hip/hip_runtime.h>

typedef __bf16 bf16;
typedef __bf16 bf16x8 __attribute__((ext_vector_type(8)));
typedef __bf16 bf16x4 __attribute__((ext_vector_type(4)));
typedef float f32x4 __attribute__((ext_vector_type(4)));

static __device__ __forceinline__ bf16x8 ld8(const bf16* p) {
    return *reinterpret_cast<const bf16x8*>(p);
}
static __device__ __forceinline__ bf16x4 ld4(const bf16* p) {
    return *reinterpret_cast<const bf16x4*>(p);
}
static __device__ __forceinline__ bf16x8 zero8() {
    bf16x8 v;
#pragma unroll
    for (int i = 0; i < 8; ++i) v[i] = (bf16)0.f;
    return v;
}

#define MFMA16(a, b, c) __builtin_amdgcn_mfma_f32_16x16x32_bf16((a), (b), (c), 0, 0, 0)

// ---------------------------------------------------------------------------
// prep: weight fp32->bf16 conversion with pad/scatter, plus bias table gather.
//   wkv  [384][192], wq [256][192], wproj [256][192] (head-padded K),
//   wfc1 [768][192], wfc2 [256][736]
//   biast[h][q(256)][key(576)] bf16 = rpb[rpi[q][key]][h]   (key contiguous)
// ---------------------------------------------------------------------------
__global__ __launch_bounds__(256) void prep_kernel(
    const float* __restrict__ kv_w, const float* __restrict__ q_w,
    const float* __restrict__ proj_w, const float* __restrict__ fc1_w,
    const float* __restrict__ fc2_w, const float* __restrict__ rpb,
    const int* __restrict__ rpi,
    bf16* __restrict__ wkv, bf16* __restrict__ wq, bf16* __restrict__ wproj,
    bf16* __restrict__ wfc1, bf16* __restrict__ wfc2, bf16* __restrict__ biast)
{
    int i = blockIdx.x * 256 + threadIdx.x;
    if (i < 73728) {                       // wkv
        int n = i / 192, k = i % 192;
        float v = (n < 360 && k < 180) ? kv_w[n * 180 + k] : 0.f;
        wkv[i] = (bf16)v;
    } else if (i < 122880) {               // wq
        int j = i - 73728; int n = j / 192, k = j % 192;
        float v = (n < 180 && k < 180) ? q_w[n * 180 + k] : 0.f;
        wq[j] = (bf16)v;
    } else if (i < 172032) {               // wproj (head-padded K)
        int j = i - 122880; int n = j / 192, k = j % 192;
        int hh = k >> 5, d = k & 31;
        float v = (n < 180 && d < 30) ? proj_w[n * 180 + hh * 30 + d] : 0.f;
        wproj[j] = (bf16)v;
    } else if (i < 319488) {               // wfc1
        int j = i - 172032; int n = j / 192, k = j % 192;
        float v = (n < 720 && k < 180) ? fc1_w[n * 180 + k] : 0.f;
        wfc1[j] = (bf16)v;
    } else if (i < 507904) {               // wfc2
        int j = i - 319488; int n = j / 736, k = j % 736;
        float v = (n < 180 && k < 720) ? fc2_w[n * 720 + k] : 0.f;
        wfc2[j] = (bf16)v;
    } else if (i < 1392640) {              // bias table [h][q][key]
        int t = i - 507904;
        int h = t / 147456, rem = t % 147456;
        int q = rem / 576, key = rem % 576;
        biast[t] = (bf16)rpb[rpi[q * 576 + key] * 6 + h];
    }
}

// ---------------------------------------------------------------------------
// LayerNorm: one wave per row of 180 fp32 -> bf16 [row][192] (tail zeroed).
// ---------------------------------------------------------------------------
__global__ __launch_bounds__(256) void ln_kernel(
    const float* __restrict__ srcA, const float* __restrict__ srcB,
    const float* __restrict__ g, const float* __restrict__ b,
    bf16* __restrict__ dst)
{
    int wave = threadIdx.x >> 6, lane = threadIdx.x & 63;
    int row = blockIdx.x * 4 + wave;
    const float* sp = (row < 16384) ? (srcA + row * 180) : (srcB + (row - 16384) * 180);
    float v0 = sp[lane];
    float v1 = sp[lane + 64];
    float v2 = (lane < 52) ? sp[lane + 128] : 0.f;
    float s = v0 + v1 + v2;
    float sq = v0 * v0 + v1 * v1 + v2 * v2;
#pragma unroll
    for (int m = 32; m >= 1; m >>= 1) {
        s += __shfl_xor(s, m);
        sq += __shfl_xor(sq, m);
    }
    float mean = s * (1.f / 180.f);
    float var = sq * (1.f / 180.f) - mean * mean;
    float rs = rsqrtf(var + 1e-5f);
    bf16* dp = dst + (long)row * 192;
    dp[lane] = (bf16)((v0 - mean) * rs * g[lane] + b[lane]);
    dp[lane + 64] = (bf16)((v1 - mean) * rs * g[lane + 64] + b[lane + 64]);
    float o2 = (lane < 52) ? ((v2 - mean) * rs * g[lane + 128] + b[lane + 128]) : 0.f;
    dp[lane + 128] = (bf16)o2;
}

// ---------------------------------------------------------------------------
// Fused kv-proj + q-proj GEMM. Direct-global MFMA, 128x128 tile, K=192.
// ---------------------------------------------------------------------------
__global__ __launch_bounds__(256) void gemm_kvq(
    const bf16* __restrict__ xn, const bf16* __restrict__ yn,
    const bf16* __restrict__ wkv, const bf16* __restrict__ wq,
    const float* __restrict__ kv_b, const float* __restrict__ q_b,
    bf16* __restrict__ kvbuf, bf16* __restrict__ qbuf)
{
    const int tid = threadIdx.x, wave = tid >> 6, lane = tid & 63;
    const int llo = lane & 15, quad = lane >> 4;
    const bool isq = blockIdx.y >= 3;
    const bf16* A = isq ? yn : xn;
    const bf16* W = isq ? wq : wkv;
    const float* bias = isq ? q_b : kv_b;
    const int tm = blockIdx.x * 128;
    const int tn = (isq ? (blockIdx.y - 3) : blockIdx.y) * 128;
    const int wm = (wave >> 1) * 64, wn = (wave & 1) * 64;

    f32x4 acc[4][4];
#pragma unroll
    for (int mt = 0; mt < 4; ++mt)
#pragma unroll
        for (int nt = 0; nt < 4; ++nt)
#pragma unroll
            for (int r = 0; r < 4; ++r) acc[mt][nt][r] = 0.f;

    for (int kt = 0; kt < 6; ++kt) {
        bf16x8 a[4], b[4];
#pragma unroll
        for (int mt = 0; mt < 4; ++mt)
            a[mt] = ld8(A + (long)(tm + wm + mt * 16 + llo) * 192 + kt * 32 + quad * 8);
#pragma unroll
        for (int nt = 0; nt < 4; ++nt)
            b[nt] = ld8(W + (long)(tn + wn + nt * 16 + llo) * 192 + kt * 32 + quad * 8);
#pragma unroll
        for (int mt = 0; mt < 4; ++mt)
#pragma unroll
            for (int nt = 0; nt < 4; ++nt)
                acc[mt][nt] = MFMA16(a[mt], b[nt], acc[mt][nt]);
    }

#pragma unroll
    for (int mt = 0; mt < 4; ++mt)
#pragma unroll
        for (int nt = 0; nt < 4; ++nt)
#pragma unroll
            for (int r = 0; r < 4; ++r) {
                int m = tm + wm + mt * 16 + quad * 4 + r;
                int n = tn + wn + nt * 16 + llo;
                if (!isq) {
                    if (n < 360) {
                        float v = acc[mt][nt][r] + bias[n];
                        int nn = n % 180;
                        int col = (n / 180) * 192 + (nn / 30) * 32 + (nn % 30);
                        kvbuf[(long)m * 384 + col] = (bf16)v;
                    }
                } else {
                    if (n < 180) {
                        float v = (acc[mt][nt][r] + bias[n]) * 0.18257418583505537f;
                        int col = (n / 30) * 32 + (n % 30);
                        qbuf[(long)m * 192 + col] = (bf16)v;
                    }
                }
            }
}

// ---------------------------------------------------------------------------
// Attention v3: transposed-S formulation, shuffle-based state broadcast.
// Block = (window, head), 8 waves; wave handles 32 queries.
// S^T = K·Q^T  (C-layout: col=query (lane llo), row=key (quad*4+r))
//   -> softmax reduction over keys is in-lane + 2 quad shuffles.
// alpha / 1/l move from col-layout (per-llo) to row-layout (per quad*4+r)
// via __shfl with computed source lane quad*4+r (all quads' copies converged).
// ---------------------------------------------------------------------------
__global__ __launch_bounds__(512) void attn_kernel(
    const bf16* __restrict__ qbuf,   // [16384][192] head-padded, pre-scaled
    const bf16* __restrict__ kvbuf,  // [16384][384] K at +0, V at +192
    const bf16* __restrict__ biast,  // [6][256][576]
    bf16* __restrict__ obuf)         // [16384][192] head-padded
{
    const int head = blockIdx.x % 6;
    const int win = blockIdx.x / 6;
    const int bb = win / 16, wi = (win % 16) / 4, wj = win % 4;
    const int tid = threadIdx.x;
    const int wave = tid >> 6, lane = tid & 63;
    const int llo = lane & 15, quad = lane >> 4;

    __shared__ bf16 Vt[32][72];        // V chunk transposed: [d][key]
    __shared__ bf16 Ps[8][32][72];     // per-wave P: [query][key]

    // Q B-fragments: lane reads Q[query=wave*32+qt*16+llo][d=quad*8..]
    bf16x8 qf[2];
#pragma unroll
    for (int qt = 0; qt < 2; ++qt) {
        int q = wave * 32 + qt * 16 + llo;
        int gr = bb * 4096 + (wi * 16 + (q >> 4)) * 64 + (wj * 16 + (q & 15));
        qf[qt] = ld8(qbuf + (long)gr * 192 + head * 32 + quad * 8);
    }

    f32x4 o[2][2];                     // [query-tile][d-tile]
    float m_run[2], l_run[2];
#pragma unroll
    for (int mt = 0; mt < 2; ++mt) {
        m_run[mt] = -1e30f; l_run[mt] = 0.f;
#pragma unroll
        for (int n2 = 0; n2 < 2; ++n2)
#pragma unroll
            for (int r = 0; r < 4; ++r) o[mt][n2][r] = 0.f;
    }

    for (int c = 0; c < 9; ++c) {
        const int kb = c * 64;
        __syncthreads();               // prior PV reads of Vt done
        if (tid < 256) {               // stage V chunk transposed
            int key = kb + (tid >> 2);
            int dq = tid & 3;
            int a = key / 24, w2 = key % 24;
            int gy = wi * 16 + a - 4, gx = wj * 16 + w2 - 4;
            bf16x8 v = zero8();
            if ((unsigned)gy < 64u && (unsigned)gx < 64u) {
                int gr = bb * 4096 + gy * 64 + gx;
                v = ld8(kvbuf + (long)gr * 384 + 192 + head * 32 + dq * 8);
            }
            int kk = (tid >> 2);
#pragma unroll
            for (int j = 0; j < 8; ++j) Vt[dq * 8 + j][kk] = v[j];
        }
        __syncthreads();               // Vt ready

        // ---- K A-fragments + S^T = K·Q^T ----
        bf16x8 kf[4];
#pragma unroll
        for (int kt = 0; kt < 4; ++kt) {
            int key = kb + kt * 16 + llo;
            int a = key / 24, w2 = key % 24;
            int gy = wi * 16 + a - 4, gx = wj * 16 + w2 - 4;
            bf16x8 kv = zero8();
            if ((unsigned)gy < 64u && (unsigned)gx < 64u)
                kv = ld8(kvbuf + (long)(bb * 4096 + gy * 64 + gx) * 384 + head * 32 + quad * 8);
            kf[kt] = kv;
        }
        f32x4 s[4][2];                 // [key-tile][query-tile]
#pragma unroll
        for (int kt = 0; kt < 4; ++kt)
#pragma unroll
            for (int qt = 0; qt < 2; ++qt) {
                f32x4 zc;
                zc[0] = 0.f; zc[1] = 0.f; zc[2] = 0.f; zc[3] = 0.f;
                s[kt][qt] = MFMA16(kf[kt], qf[qt], zc);
            }

        // ---- + bias: biast[h][q][key], 4 contiguous keys per reg group ----
#pragma unroll
        for (int kt = 0; kt < 4; ++kt)
#pragma unroll
            for (int qt = 0; qt < 2; ++qt) {
                int q = wave * 32 + qt * 16 + llo;
                bf16x4 bv = ld4(biast + ((long)head * 256 + q) * 576 + kb + kt * 16 + quad * 4);
#pragma unroll
                for (int r = 0; r < 4; ++r) s[kt][qt][r] += (float)bv[r];
            }

        // ---- online softmax: keys in-lane + across quads ----
        float alpha_q[2];
#pragma unroll
        for (int qt = 0; qt < 2; ++qt) {
            float mx = s[0][qt][0];
#pragma unroll
            for (int kt = 0; kt < 4; ++kt)
#pragma unroll
                for (int r = 0; r < 4; ++r) mx = fmaxf(mx, s[kt][qt][r]);
            mx = fmaxf(mx, __shfl_xor(mx, 16));
            mx = fmaxf(mx, __shfl_xor(mx, 32));
            float m_new = fmaxf(m_run[qt], mx);
            float alpha = __expf(m_run[qt] - m_new);
            float ls = 0.f;
#pragma unroll
            for (int kt = 0; kt < 4; ++kt)
#pragma unroll
                for (int r = 0; r < 4; ++r) {
                    float p = __expf(s[kt][qt][r] - m_new);
                    s[kt][qt][r] = p;
                    ls += p;
                }
            ls += __shfl_xor(ls, 16);
            ls += __shfl_xor(ls, 32);
            l_run[qt] = l_run[qt] * alpha + ls;
            m_run[qt] = m_new;
            alpha_q[qt] = alpha;
        }
        // rescale O: alpha for query mt*16+quad*4+r lives at lane quad*4+r
#pragma unroll
        for (int mt = 0; mt < 2; ++mt)
#pragma unroll
            for (int r = 0; r < 4; ++r) {
                float a = __shfl(alpha_q[mt], quad * 4 + r);
                o[mt][0][r] *= a;
                o[mt][1][r] *= a;
            }

        // ---- pack P -> LDS [query][key] (b64 stores, wave-private) ----
#pragma unroll
        for (int kt = 0; kt < 4; ++kt)
#pragma unroll
            for (int qt = 0; qt < 2; ++qt) {
                bf16x4 pv;
#pragma unroll
                for (int r = 0; r < 4; ++r) pv[r] = (bf16)s[kt][qt][r];
                *reinterpret_cast<bf16x4*>(&Ps[wave][qt * 16 + llo][kt * 16 + quad * 4]) = pv;
            }
        __syncthreads();               // P visible (defensive; Ps is wave-private)

        // ---- O += P·V  (A = Ps[query][key], B = Vt[d][key]) ----
#pragma unroll
        for (int kt2 = 0; kt2 < 2; ++kt2) {
            bf16x8 pa[2], vb[2];
#pragma unroll
            for (int mt = 0; mt < 2; ++mt)
                pa[mt] = ld8(&Ps[wave][mt * 16 + llo][kt2 * 32 + quad * 8]);
#pragma unroll
            for (int n2 = 0; n2 < 2; ++n2)
                vb[n2] = ld8(&Vt[n2 * 16 + llo][kt2 * 32 + quad * 8]);
#pragma unroll
            for (int mt = 0; mt < 2; ++mt)
#pragma unroll
                for (int n2 = 0; n2 < 2; ++n2)
                    o[mt][n2] = MFMA16(pa[mt], vb[n2], o[mt][n2]);
        }
    }

    // ---- normalize (1/l via computed-lane shuffle) and write out ----
    float linv[2];
#pragma unroll
    for (int qt = 0; qt < 2; ++qt) linv[qt] = 1.f / l_run[qt];
#pragma unroll
    for (int mt = 0; mt < 2; ++mt)
#pragma unroll
        for (int r = 0; r < 4; ++r) {
            float li = __shfl(linv[mt], quad * 4 + r);
            int q = wave * 32 + mt * 16 + quad * 4 + r;
            int gr = bb * 4096 + (wi * 16 + (q >> 4)) * 64 + (wj * 16 + (q & 15));
#pragma unroll
            for (int n2 = 0; n2 < 2; ++n2)
                obuf[(long)gr * 192 + head * 32 + n2 * 16 + llo] = (bf16)(o[mt][n2][r] * li);
        }
}

// ---------------------------------------------------------------------------
// Generic epilogue GEMM: C = A[M][KPAD] @ W[N][KPAD]^T + bias
// MODE 2: fp32 out = v + resid   (proj+residual, fc2+residual)
// MODE 3: bf16 out = gelu(v)     (fc1)
// ---------------------------------------------------------------------------
template <int KPAD, int NREAL, int OSTRIDE, int MODE>
__global__ __launch_bounds__(256) void gemm_ep(
    const bf16* __restrict__ A, const bf16* __restrict__ W,
    const float* __restrict__ bias, const float* __restrict__ resid,
    void* __restrict__ outp)
{
    const int tid = threadIdx.x, wave = tid >> 6, lane = tid & 63;
    const int llo = lane & 15, quad = lane >> 4;
    const int tm = blockIdx.x * 128;
    const int tn = blockIdx.y * 128;
    const int wm = (wave >> 1) * 64, wn = (wave & 1) * 64;

    f32x4 acc[4][4];
#pragma unroll
    for (int mt = 0; mt < 4; ++mt)
#pragma unroll
        for (int nt = 0; nt < 4; ++nt)
#pragma unroll
            for (int r = 0; r < 4; ++r) acc[mt][nt][r] = 0.f;

    for (int kt = 0; kt < KPAD / 32; ++kt) {
        bf16x8 a[4], b[4];
#pragma unroll
        for (int mt = 0; mt < 4; ++mt)
            a[mt] = ld8(A + (long)(tm + wm + mt * 16 + llo) * KPAD + kt * 32 + quad * 8);
#pragma unroll
        for (int nt = 0; nt < 4; ++nt)
            b[nt] = ld8(W + (long)(tn + wn + nt * 16 + llo) * KPAD + kt * 32 + quad * 8);
#pragma unroll
        for (int mt = 0; mt < 4; ++mt)
#pragma unroll
            for (int nt = 0; nt < 4; ++nt)
                acc[mt][nt] = MFMA16(a[mt], b[nt], acc[mt][nt]);
    }

#pragma unroll
    for (int mt = 0; mt < 4; ++mt)
#pragma unroll
        for (int nt = 0; nt < 4; ++nt)
#pragma unroll
            for (int r = 0; r < 4; ++r) {
                int m = tm + wm + mt * 16 + quad * 4 + r;
                int n = tn + wn + nt * 16 + llo;
                if (n >= NREAL) continue;
                float v = acc[mt][nt][r] + bias[n];
                if (MODE == 2) {
                    ((float*)outp)[(long)m * OSTRIDE + n] = v + resid[(long)m * 180 + n];
                } else {
                    float gel = 0.5f * v * (1.f + erff(v * 0.7071067811865475f));
                    ((bf16*)outp)[(long)m * OSTRIDE + n] = (bf16)gel;
                }
            }
}

// ---------------------------------------------------------------------------
extern "C" void kernel_launch(void* const* d_in, const int* in_sizes, int n_in,
                              void* d_out, int out_size, void* d_ws, size_t ws_size,
                              hipStream_t stream) {
    const float* x      = (const float*)d_in[0];
    const float* y      = (const float*)d_in[1];
    const float* n1g    = (const float*)d_in[2];
    const float* n1b    = (const float*)d_in[3];
    const float* kv_w   = (const float*)d_in[4];
    const float* kv_b   = (const float*)d_in[5];
    const float* q_w    = (const float*)d_in[6];
    const float* q_b    = (const float*)d_in[7];
    const float* rpb    = (const float*)d_in[8];
    const float* proj_w = (const float*)d_in[9];
    const float* proj_b = (const float*)d_in[10];
    const float* n2g    = (const float*)d_in[11];
    const float* n2b    = (const float*)d_in[12];
    const float* fc1_w  = (const float*)d_in[13];
    const float* fc1_b  = (const float*)d_in[14];
    const float* fc2_w  = (const float*)d_in[15];
    const float* fc2_b  = (const float*)d_in[16];
    const int*   rpi    = (const int*)d_in[17];

    char* ws = (char*)d_ws;
    bf16* xn    = (bf16*)(ws + 0);          // [32768][192] = xn (16384) + yn (16384)
    bf16* yn    = (bf16*)(ws + 6291456);
    bf16* qbuf  = (bf16*)(ws + 12582912);   // [16384][192]
    bf16* kvbuf = (bf16*)(ws + 18874368);   // [16384][384]
    bf16* obuf  = (bf16*)(ws + 31457280);   // [16384][192]
    float* xo   = (float*)(ws + 37748736);  // [16384][180] fp32
    bf16* biast = (bf16*)(ws + 49545216);   // [6][256][576]
    bf16* wkv   = (bf16*)(ws + 51314688);
    bf16* wq    = (bf16*)(ws + 51462144);
    bf16* wproj = (bf16*)(ws + 51560448);
    bf16* wfc1  = (bf16*)(ws + 51658752);
    bf16* wfc2  = (bf16*)(ws + 51953664);
    bf16* hmid  = (bf16*)(ws + 6291456);    // reuse yn/qbuf/kvbuf region
    bf16* xn2   = xn;                       // xn dead after gemm_kvq

    prep_kernel<<<5440, 256, 0, stream>>>(kv_w, q_w, proj_w, fc1_w, fc2_w, rpb, rpi,
                                          wkv, wq, wproj, wfc1, wfc2, biast);
    ln_kernel<<<8192, 256, 0, stream>>>(x, y, n1g, n1b, xn);
    gemm_kvq<<<dim3(128, 5), 256, 0, stream>>>(xn, yn, wkv, wq, kv_b, q_b, kvbuf, qbuf);
    attn_kernel<<<384, 512, 0, stream>>>(qbuf, kvbuf, biast, obuf);
    gemm_ep<192, 180, 180, 2><<<dim3(128, 2), 256, 0, stream>>>(obuf, wproj, proj_b, x, xo);
    ln_kernel<<<4096, 256, 0, stream>>>(xo, xo, n2g, n2b, xn2);
    gemm_ep<192, 720, 736, 3><<<dim3(128, 6), 256, 0, stream>>>(xn2, wfc1, fc1_b, nullptr, hmid);
    gemm_ep<736, 180, 180, 2><<<dim3(128, 2), 256, 0, stream>>>(hmid, wfc2, fc2_b, xo, (float*)d_out);
}

// Round 4
// 259.322 us; speedup vs baseline: 1.1477x; 1.0714x over previous
//
#include <hip/hip_runtime.h>

typedef __bf16 bf16;
typedef __bf16 bf16x8 __attribute__((ext_vector_type(8)));
typedef __bf16 bf16x4 __attribute__((ext_vector_type(4)));
typedef float f32x4 __attribute__((ext_vector_type(4)));

static __device__ __forceinline__ bf16x8 ld8(const bf16* p) {
    return *reinterpret_cast<const bf16x8*>(p);
}
static __device__ __forceinline__ bf16x4 ld4(const bf16* p) {
    return *reinterpret_cast<const bf16x4*>(p);
}
static __device__ __forceinline__ bf16x8 zero8() {
    bf16x8 v;
#pragma unroll
    for (int i = 0; i < 8; ++i) v[i] = (bf16)0.f;
    return v;
}

#define MFMA16(a, b, c) __builtin_amdgcn_mfma_f32_16x16x32_bf16((a), (b), (c), 0, 0, 0)

// ---------------------------------------------------------------------------
// prep: weight fp32->bf16 conversion with pad/scatter, plus bias table gather.
//   wkv  [384][192], wq [256][192], wproj [256][192] (head-padded K),
//   wfc1 [768][192], wfc2 [256][736]
//   biast[h][q(256)][key(576)] bf16 = rpb[rpi[q][key]][h]   (key contiguous)
// ---------------------------------------------------------------------------
__global__ __launch_bounds__(256) void prep_kernel(
    const float* __restrict__ kv_w, const float* __restrict__ q_w,
    const float* __restrict__ proj_w, const float* __restrict__ fc1_w,
    const float* __restrict__ fc2_w, const float* __restrict__ rpb,
    const int* __restrict__ rpi,
    bf16* __restrict__ wkv, bf16* __restrict__ wq, bf16* __restrict__ wproj,
    bf16* __restrict__ wfc1, bf16* __restrict__ wfc2, bf16* __restrict__ biast)
{
    int i = blockIdx.x * 256 + threadIdx.x;
    if (i < 73728) {                       // wkv
        int n = i / 192, k = i % 192;
        float v = (n < 360 && k < 180) ? kv_w[n * 180 + k] : 0.f;
        wkv[i] = (bf16)v;
    } else if (i < 122880) {               // wq
        int j = i - 73728; int n = j / 192, k = j % 192;
        float v = (n < 180 && k < 180) ? q_w[n * 180 + k] : 0.f;
        wq[j] = (bf16)v;
    } else if (i < 172032) {               // wproj (head-padded K)
        int j = i - 122880; int n = j / 192, k = j % 192;
        int hh = k >> 5, d = k & 31;
        float v = (n < 180 && d < 30) ? proj_w[n * 180 + hh * 30 + d] : 0.f;
        wproj[j] = (bf16)v;
    } else if (i < 319488) {               // wfc1
        int j = i - 172032; int n = j / 192, k = j % 192;
        float v = (n < 720 && k < 180) ? fc1_w[n * 180 + k] : 0.f;
        wfc1[j] = (bf16)v;
    } else if (i < 507904) {               // wfc2
        int j = i - 319488; int n = j / 736, k = j % 736;
        float v = (n < 180 && k < 720) ? fc2_w[n * 720 + k] : 0.f;
        wfc2[j] = (bf16)v;
    } else if (i < 1392640) {              // bias table [h][q][key]
        int t = i - 507904;
        int h = t / 147456, rem = t % 147456;
        int q = rem / 576, key = rem % 576;
        biast[t] = (bf16)rpb[rpi[q * 576 + key] * 6 + h];
    }
}

// ---------------------------------------------------------------------------
// LayerNorm: one wave per row of 180 fp32 -> bf16 [row][192] (tail zeroed).
// ---------------------------------------------------------------------------
__global__ __launch_bounds__(256) void ln_kernel(
    const float* __restrict__ srcA, const float* __restrict__ srcB,
    const float* __restrict__ g, const float* __restrict__ b,
    bf16* __restrict__ dst)
{
    int wave = threadIdx.x >> 6, lane = threadIdx.x & 63;
    int row = blockIdx.x * 4 + wave;
    const float* sp = (row < 16384) ? (srcA + row * 180) : (srcB + (row - 16384) * 180);
    float v0 = sp[lane];
    float v1 = sp[lane + 64];
    float v2 = (lane < 52) ? sp[lane + 128] : 0.f;
    float s = v0 + v1 + v2;
    float sq = v0 * v0 + v1 * v1 + v2 * v2;
#pragma unroll
    for (int m = 32; m >= 1; m >>= 1) {
        s += __shfl_xor(s, m);
        sq += __shfl_xor(sq, m);
    }
    float mean = s * (1.f / 180.f);
    float var = sq * (1.f / 180.f) - mean * mean;
    float rs = rsqrtf(var + 1e-5f);
    bf16* dp = dst + (long)row * 192;
    dp[lane] = (bf16)((v0 - mean) * rs * g[lane] + b[lane]);
    dp[lane + 64] = (bf16)((v1 - mean) * rs * g[lane + 64] + b[lane + 64]);
    float o2 = (lane < 52) ? ((v2 - mean) * rs * g[lane + 128] + b[lane + 128]) : 0.f;
    dp[lane + 128] = (bf16)o2;
}

// ---------------------------------------------------------------------------
// Fused kv-proj + q-proj GEMM. Direct-global MFMA, 128x128 tile, K=192.
// ---------------------------------------------------------------------------
__global__ __launch_bounds__(256) void gemm_kvq(
    const bf16* __restrict__ xn, const bf16* __restrict__ yn,
    const bf16* __restrict__ wkv, const bf16* __restrict__ wq,
    const float* __restrict__ kv_b, const float* __restrict__ q_b,
    bf16* __restrict__ kvbuf, bf16* __restrict__ qbuf)
{
    const int tid = threadIdx.x, wave = tid >> 6, lane = tid & 63;
    const int llo = lane & 15, quad = lane >> 4;
    const bool isq = blockIdx.y >= 3;
    const bf16* A = isq ? yn : xn;
    const bf16* W = isq ? wq : wkv;
    const float* bias = isq ? q_b : kv_b;
    const int tm = blockIdx.x * 128;
    const int tn = (isq ? (blockIdx.y - 3) : blockIdx.y) * 128;
    const int wm = (wave >> 1) * 64, wn = (wave & 1) * 64;

    f32x4 acc[4][4];
#pragma unroll
    for (int mt = 0; mt < 4; ++mt)
#pragma unroll
        for (int nt = 0; nt < 4; ++nt)
#pragma unroll
            for (int r = 0; r < 4; ++r) acc[mt][nt][r] = 0.f;

    for (int kt = 0; kt < 6; ++kt) {
        bf16x8 a[4], b[4];
#pragma unroll
        for (int mt = 0; mt < 4; ++mt)
            a[mt] = ld8(A + (long)(tm + wm + mt * 16 + llo) * 192 + kt * 32 + quad * 8);
#pragma unroll
        for (int nt = 0; nt < 4; ++nt)
            b[nt] = ld8(W + (long)(tn + wn + nt * 16 + llo) * 192 + kt * 32 + quad * 8);
#pragma unroll
        for (int mt = 0; mt < 4; ++mt)
#pragma unroll
            for (int nt = 0; nt < 4; ++nt)
                acc[mt][nt] = MFMA16(a[mt], b[nt], acc[mt][nt]);
    }

#pragma unroll
    for (int mt = 0; mt < 4; ++mt)
#pragma unroll
        for (int nt = 0; nt < 4; ++nt)
#pragma unroll
            for (int r = 0; r < 4; ++r) {
                int m = tm + wm + mt * 16 + quad * 4 + r;
                int n = tn + wn + nt * 16 + llo;
                if (!isq) {
                    if (n < 360) {
                        float v = acc[mt][nt][r] + bias[n];
                        int nn = n % 180;
                        int col = (n / 180) * 192 + (nn / 30) * 32 + (nn % 30);
                        kvbuf[(long)m * 384 + col] = (bf16)v;
                    }
                } else {
                    if (n < 180) {
                        float v = (acc[mt][nt][r] + bias[n]) * 0.18257418583505537f;
                        int col = (n / 30) * 32 + (n % 30);
                        qbuf[(long)m * 192 + col] = (bf16)v;
                    }
                }
            }
}

// ---------------------------------------------------------------------------
// Attention v4: transposed-S + LDS-staged K.
// Grid = (window, head, qhalf) = 768 blocks, 512 threads (8 waves x 16 q).
// Per chunk: 256 threads stage K -> Kc[64][40] (b128), 256 stage V -> Vt
// (transposed). All waves read kf from LDS (kills 8x global K redundancy).
// S^T = K·Q^T (col=query, row=key): softmax in-lane + 2 quad shuffles.
// ---------------------------------------------------------------------------
__global__ __launch_bounds__(512, 6) void attn_kernel(
    const bf16* __restrict__ qbuf,   // [16384][192] head-padded, pre-scaled
    const bf16* __restrict__ kvbuf,  // [16384][384] K at +0, V at +192
    const bf16* __restrict__ biast,  // [6][256][576]
    bf16* __restrict__ obuf)         // [16384][192] head-padded
{
    const int qhalf = blockIdx.x & 1;
    const int head = (blockIdx.x >> 1) % 6;
    const int win = blockIdx.x / 12;
    const int bb = win / 16, wi = (win % 16) / 4, wj = win % 4;
    const int tid = threadIdx.x;
    const int wave = tid >> 6, lane = tid & 63;
    const int llo = lane & 15, quad = lane >> 4;
    const int qbase = qhalf * 128 + wave * 16;

    __shared__ bf16 Kc[64][40];        // K chunk: [key][d], b128-stored
    __shared__ bf16 Vt[32][72];        // V chunk transposed: [d][key]
    __shared__ bf16 Ps[8][16][72];     // per-wave P: [query][key]

    // staging coords (thread u stages key tloc, d-group dq; first 256 K, rest V)
    const int u = tid & 255;
    const int tloc = u >> 2, dq = u & 3;
    const bool isV = tid >= 256;
    int aa = tloc / 24, w0 = tloc % 24;   // key = c*64 + tloc decomposed

    // Q B-frag: lane reads Q[query=qbase+llo][d=quad*8..]
    const int q0 = qbase + llo;
    const int gr_q = bb * 4096 + (wi * 16 + (q0 >> 4)) * 64 + (wj * 16 + (q0 & 15));
    const bf16x8 qf = ld8(qbuf + (long)gr_q * 192 + head * 32 + quad * 8);

    f32x4 o[2];
    float m_run = -1e30f, l_run = 0.f;
#pragma unroll
    for (int n2 = 0; n2 < 2; ++n2)
#pragma unroll
        for (int r = 0; r < 4; ++r) o[n2][r] = 0.f;

    for (int c = 0; c < 9; ++c) {
        const int kb = c * 64;
        __syncthreads();               // prior chunk's LDS reads done
        {   // stage K (tid<256) / V (tid>=256)
            int gy = wi * 16 + aa - 4, gx = wj * 16 + w0 - 4;
            bf16x8 v = zero8();
            if ((unsigned)gy < 64u && (unsigned)gx < 64u) {
                long gr = (long)(bb * 4096 + gy * 64 + gx) * 384;
                v = ld8(kvbuf + gr + (isV ? 192 : 0) + head * 32 + dq * 8);
            }
            if (!isV) {
                *reinterpret_cast<bf16x8*>(&Kc[tloc][dq * 8]) = v;
            } else {
#pragma unroll
                for (int j = 0; j < 8; ++j) Vt[dq * 8 + j][tloc] = v[j];
            }
            // advance key by 64: 64 = 2*24 + 16
            w0 += 16; aa += 2;
            if (w0 >= 24) { w0 -= 24; ++aa; }
        }
        __syncthreads();               // Kc/Vt ready

        // ---- S^T = K·Q^T  (A = Kc[key][d], B = qf) ----
        f32x4 s[4];
#pragma unroll
        for (int kt = 0; kt < 4; ++kt) {
            bf16x8 kf = ld8(&Kc[kt * 16 + llo][quad * 8]);
            f32x4 zc;
            zc[0] = 0.f; zc[1] = 0.f; zc[2] = 0.f; zc[3] = 0.f;
            s[kt] = MFMA16(kf, qf, zc);
        }

        // ---- + bias: biast[h][q][key], 4 contiguous keys per reg group ----
#pragma unroll
        for (int kt = 0; kt < 4; ++kt) {
            bf16x4 bv = ld4(biast + ((long)head * 256 + q0) * 576 + kb + kt * 16 + quad * 4);
#pragma unroll
            for (int r = 0; r < 4; ++r) s[kt][r] += (float)bv[r];
        }

        // ---- online softmax: keys in-lane + across quads ----
        float mx = s[0][0];
#pragma unroll
        for (int kt = 0; kt < 4; ++kt)
#pragma unroll
            for (int r = 0; r < 4; ++r) mx = fmaxf(mx, s[kt][r]);
        mx = fmaxf(mx, __shfl_xor(mx, 16));
        mx = fmaxf(mx, __shfl_xor(mx, 32));
        float m_new = fmaxf(m_run, mx);
        float alpha = __expf(m_run - m_new);
        float ls = 0.f;
#pragma unroll
        for (int kt = 0; kt < 4; ++kt)
#pragma unroll
            for (int r = 0; r < 4; ++r) {
                float p = __expf(s[kt][r] - m_new);
                s[kt][r] = p;
                ls += p;
            }
        ls += __shfl_xor(ls, 16);
        ls += __shfl_xor(ls, 32);
        l_run = l_run * alpha + ls;
        m_run = m_new;

        // rescale O: alpha for query quad*4+r lives at lane quad*4+r
#pragma unroll
        for (int r = 0; r < 4; ++r) {
            float a = __shfl(alpha, quad * 4 + r);
            o[0][r] *= a;
            o[1][r] *= a;
        }

        // ---- pack P -> LDS [query][key] (b64 stores, wave-private) ----
#pragma unroll
        for (int kt = 0; kt < 4; ++kt) {
            bf16x4 pv;
#pragma unroll
            for (int r = 0; r < 4; ++r) pv[r] = (bf16)s[kt][r];
            *reinterpret_cast<bf16x4*>(&Ps[wave][llo][kt * 16 + quad * 4]) = pv;
        }

        // ---- O += P·V  (A = Ps[query][key], B = Vt[d][key]) ----
#pragma unroll
        for (int kt2 = 0; kt2 < 2; ++kt2) {
            bf16x8 pa = ld8(&Ps[wave][llo][kt2 * 32 + quad * 8]);
#pragma unroll
            for (int n2 = 0; n2 < 2; ++n2) {
                bf16x8 vb = ld8(&Vt[n2 * 16 + llo][kt2 * 32 + quad * 8]);
                o[n2] = MFMA16(pa, vb, o[n2]);
            }
        }
    }

    // ---- normalize (1/l via computed-lane shuffle) and write out ----
    float linv = 1.f / l_run;
#pragma unroll
    for (int r = 0; r < 4; ++r) {
        float li = __shfl(linv, quad * 4 + r);
        int q = qbase + quad * 4 + r;
        int gr = bb * 4096 + (wi * 16 + (q >> 4)) * 64 + (wj * 16 + (q & 15));
#pragma unroll
        for (int n2 = 0; n2 < 2; ++n2)
            obuf[(long)gr * 192 + head * 32 + n2 * 16 + llo] = (bf16)(o[n2][r] * li);
    }
}

// ---------------------------------------------------------------------------
// Generic epilogue GEMM: C = A[M][KPAD] @ W[N][KPAD]^T + bias
// MODE 2: fp32 out = v + resid   (proj+residual, fc2+residual)
// MODE 3: bf16 out = gelu(v)     (fc1)
// ---------------------------------------------------------------------------
template <int KPAD, int NREAL, int OSTRIDE, int MODE>
__global__ __launch_bounds__(256) void gemm_ep(
    const bf16* __restrict__ A, const bf16* __restrict__ W,
    const float* __restrict__ bias, const float* __restrict__ resid,
    void* __restrict__ outp)
{
    const int tid = threadIdx.x, wave = tid >> 6, lane = tid & 63;
    const int llo = lane & 15, quad = lane >> 4;
    const int tm = blockIdx.x * 128;
    const int tn = blockIdx.y * 128;
    const int wm = (wave >> 1) * 64, wn = (wave & 1) * 64;

    f32x4 acc[4][4];
#pragma unroll
    for (int mt = 0; mt < 4; ++mt)
#pragma unroll
        for (int nt = 0; nt < 4; ++nt)
#pragma unroll
            for (int r = 0; r < 4; ++r) acc[mt][nt][r] = 0.f;

    for (int kt = 0; kt < KPAD / 32; ++kt) {
        bf16x8 a[4], b[4];
#pragma unroll
        for (int mt = 0; mt < 4; ++mt)
            a[mt] = ld8(A + (long)(tm + wm + mt * 16 + llo) * KPAD + kt * 32 + quad * 8);
#pragma unroll
        for (int nt = 0; nt < 4; ++nt)
            b[nt] = ld8(W + (long)(tn + wn + nt * 16 + llo) * KPAD + kt * 32 + quad * 8);
#pragma unroll
        for (int mt = 0; mt < 4; ++mt)
#pragma unroll
            for (int nt = 0; nt < 4; ++nt)
                acc[mt][nt] = MFMA16(a[mt], b[nt], acc[mt][nt]);
    }

#pragma unroll
    for (int mt = 0; mt < 4; ++mt)
#pragma unroll
        for (int nt = 0; nt < 4; ++nt)
#pragma unroll
            for (int r = 0; r < 4; ++r) {
                int m = tm + wm + mt * 16 + quad * 4 + r;
                int n = tn + wn + nt * 16 + llo;
                if (n >= NREAL) continue;
                float v = acc[mt][nt][r] + bias[n];
                if (MODE == 2) {
                    ((float*)outp)[(long)m * OSTRIDE + n] = v + resid[(long)m * 180 + n];
                } else {
                    float gel = 0.5f * v * (1.f + erff(v * 0.7071067811865475f));
                    ((bf16*)outp)[(long)m * OSTRIDE + n] = (bf16)gel;
                }
            }
}

// ---------------------------------------------------------------------------
extern "C" void kernel_launch(void* const* d_in, const int* in_sizes, int n_in,
                              void* d_out, int out_size, void* d_ws, size_t ws_size,
                              hipStream_t stream) {
    const float* x      = (const float*)d_in[0];
    const float* y      = (const float*)d_in[1];
    const float* n1g    = (const float*)d_in[2];
    const float* n1b    = (const float*)d_in[3];
    const float* kv_w   = (const float*)d_in[4];
    const float* kv_b   = (const float*)d_in[5];
    const float* q_w    = (const float*)d_in[6];
    const float* q_b    = (const float*)d_in[7];
    const float* rpb    = (const float*)d_in[8];
    const float* proj_w = (const float*)d_in[9];
    const float* proj_b = (const float*)d_in[10];
    const float* n2g    = (const float*)d_in[11];
    const float* n2b    = (const float*)d_in[12];
    const float* fc1_w  = (const float*)d_in[13];
    const float* fc1_b  = (const float*)d_in[14];
    const float* fc2_w  = (const float*)d_in[15];
    const float* fc2_b  = (const float*)d_in[16];
    const int*   rpi    = (const int*)d_in[17];

    char* ws = (char*)d_ws;
    bf16* xn    = (bf16*)(ws + 0);          // [32768][192] = xn (16384) + yn (16384)
    bf16* yn    = (bf16*)(ws + 6291456);
    bf16* qbuf  = (bf16*)(ws + 12582912);   // [16384][192]
    bf16* kvbuf = (bf16*)(ws + 18874368);   // [16384][384]
    bf16* obuf  = (bf16*)(ws + 31457280);   // [16384][192]
    float* xo   = (float*)(ws + 37748736);  // [16384][180] fp32
    bf16* biast = (bf16*)(ws + 49545216);   // [6][256][576]
    bf16* wkv   = (bf16*)(ws + 51314688);
    bf16* wq    = (bf16*)(ws + 51462144);
    bf16* wproj = (bf16*)(ws + 51560448);
    bf16* wfc1  = (bf16*)(ws + 51658752);
    bf16* wfc2  = (bf16*)(ws + 51953664);
    bf16* hmid  = (bf16*)(ws + 6291456);    // reuse yn/qbuf/kvbuf region
    bf16* xn2   = xn;                       // xn dead after gemm_kvq

    prep_kernel<<<5440, 256, 0, stream>>>(kv_w, q_w, proj_w, fc1_w, fc2_w, rpb, rpi,
                                          wkv, wq, wproj, wfc1, wfc2, biast);
    ln_kernel<<<8192, 256, 0, stream>>>(x, y, n1g, n1b, xn);
    gemm_kvq<<<dim3(128, 5), 256, 0, stream>>>(xn, yn, wkv, wq, kv_b, q_b, kvbuf, qbuf);
    attn_kernel<<<768, 512, 0, stream>>>(qbuf, kvbuf, biast, obuf);
    gemm_ep<192, 180, 180, 2><<<dim3(128, 2), 256, 0, stream>>>(obuf, wproj, proj_b, x, xo);
    ln_kernel<<<4096, 256, 0, stream>>>(xo, xo, n2g, n2b, xn2);
    gemm_ep<192, 720, 736, 3><<<dim3(128, 6), 256, 0, stream>>>(xn2, wfc1, fc1_b, nullptr, hmid);
    gemm_ep<736, 180, 180, 2><<<dim3(128, 2), 256, 0, stream>>>(hmid, wfc2, fc2_b, xo, (float*)d_out);
}